// Round 1
// baseline (26.908 us; speedup 1.0000x reference)
//
#include <hip/hip_runtime.h>
#include <stdint.h>

#define B_ 16
#define L_ 256
#define D_ 1024
#define R_ 128
#define M_ (B_*L_)   // 4096 rows of t

typedef short short8 __attribute__((ext_vector_type(8)));
typedef float f32x4 __attribute__((ext_vector_type(4)));

__device__ __forceinline__ unsigned short f2bf(float f) {
  union { float f; unsigned int u; } v; v.f = f;
  unsigned int r = v.u + 0x7FFFu + ((v.u >> 16) & 1u);  // RNE
  return (unsigned short)(r >> 16);
}
__device__ __forceinline__ float bf2f(unsigned short s) {
  union { unsigned int u; float f; } v; v.u = ((unsigned int)s) << 16;
  return v.f;
}
__device__ __forceinline__ void gload_lds16(const void* g, void* l) {
  __builtin_amdgcn_global_load_lds(
      (const __attribute__((address_space(1))) unsigned int*)g,
      (__attribute__((address_space(3))) unsigned int*)l, 16, 0, 0);
}

// ---------------- K0: P [1024][128] f32 -> PbT [128][1024] bf16 ----------------
__global__ __launch_bounds__(256) void k0_transpose_cast(
    const float* __restrict__ P, unsigned short* __restrict__ PbT) {
  int id = blockIdx.x * 256 + threadIdx.x;   // 0..16383
  int n  = id >> 7;                          // 0..127
  int kc = id & 127;                         // chunk of 8 k
  union { unsigned short s[8]; uint4 v; } u;
#pragma unroll
  for (int j = 0; j < 8; ++j) u.s[j] = f2bf(P[(kc * 8 + j) * R_ + n]);
  *reinterpret_cast<uint4*>(&PbT[n * D_ + kc * 8]) = u.v;
}

// ---------------- K1: t = X @ P  (bf16 MFMA), + row norms ----------------
// BM=16, BN=128 (full), BK=64. 512 threads = 8 waves, wave w owns cols [16w,16w+16).
__global__ __launch_bounds__(512) void k1_gemm(
    const float* __restrict__ X, const unsigned short* __restrict__ PbT,
    unsigned short* __restrict__ Tb, float* __restrict__ Nrm) {
  __shared__ unsigned short sX[2][16 * 64];    // 16 rows x 128B, swizzled
  __shared__ unsigned short sP[2][128 * 64];   // 128 rows x 128B, swizzled
  __shared__ float nacc[16][8];

  const int tid  = threadIdx.x;
  const int lane = tid & 63;
  const int w    = tid >> 6;          // wave 0..7
  const int m0   = blockIdx.x * 16;

  // X staging coords: thread covers (row, 2 consecutive k)
  const int xr = tid >> 5;            // 0..15
  const int xk = (tid & 31) * 2;      // 0..62

  f32x4 acc;
  acc[0] = 0.f; acc[1] = 0.f; acc[2] = 0.f; acc[3] = 0.f;

  auto stage = [&](int buf, int kt) {
    const int k0 = kt * 64;
    // X: load f32x2, cvt->bf16x2, swizzled ds_write_b32
    float2 xv = *reinterpret_cast<const float2*>(&X[(size_t)(m0 + xr) * D_ + k0 + xk]);
    unsigned int packed = (unsigned int)f2bf(xv.x) | ((unsigned int)f2bf(xv.y) << 16);
    int byte_in_row = (xk * 2) ^ ((xr & 7) << 4);
    reinterpret_cast<unsigned int*>(&sX[buf][0])[(xr * 128 + byte_in_row) >> 2] = packed;
    // P: global_load_lds 16B, linear LDS dest, inverse-swizzled global source
#pragma unroll
    for (int i = 0; i < 2; ++i) {
      int c = tid + 512 * i;          // chunk id 0..1023
      int row = c >> 3, ch = c & 7;
      gload_lds16(&PbT[(size_t)row * D_ + k0 + ((ch ^ (row & 7)) * 8)],
                  &sP[buf][c * 8]);
    }
  };

  auto compute = [&](int buf) {
    const char* xb = reinterpret_cast<const char*>(&sX[buf][0]);
    const char* pb = reinterpret_cast<const char*>(&sP[buf][0]);
    const int nb = w * 16;
#pragma unroll
    for (int s = 0; s < 2; ++s) {
      int koffb = s * 64 + ((lane >> 4) << 4);   // byte offset of this lane's 8 k's
      int ar = lane & 15;
      short8 a = *reinterpret_cast<const short8*>(xb + ar * 128 + (koffb ^ ((ar & 7) << 4)));
      int br = nb + (lane & 15);
      short8 b = *reinterpret_cast<const short8*>(pb + br * 128 + (koffb ^ ((br & 7) << 4)));
      acc = __builtin_amdgcn_mfma_f32_16x16x32_bf16(a, b, acc, 0, 0, 0);
    }
  };

  stage(0, 0);
  __syncthreads();
  int buf = 0;
  for (int kt = 0; kt < 16; ++kt) {
    if (kt < 15) stage(buf ^ 1, kt + 1);
    compute(buf);
    __syncthreads();
    buf ^= 1;
  }

  // epilogue: write bf16 t, accumulate norms of the ROUNDED values
  const int nb = w * 16;
  const int col = lane & 15;
#pragma unroll
  for (int q = 0; q < 4; ++q) {
    int row = ((lane >> 4) << 2) + q;
    unsigned short hv = f2bf(acc[q]);
    Tb[(size_t)(m0 + row) * R_ + nb + col] = hv;
    float tr = bf2f(hv);
    float s = tr * tr;
    s += __shfl_xor(s, 1); s += __shfl_xor(s, 2);
    s += __shfl_xor(s, 4); s += __shfl_xor(s, 8);
    if (col == 0) nacc[row][w] = s;
  }
  __syncthreads();
  if (tid < 16) {
    float t = 0.f;
#pragma unroll
    for (int i = 0; i < 8; ++i) t += nacc[tid][i];
    Nrm[m0 + tid] = t;
  }
}

// ---------------- K2: per-batch Gram + distance epilogue ----------------
// block = (batch b, i-tile it of 16 rows). 256 threads = 4 waves, wave w owns j in [64w,64w+64).
__global__ __launch_bounds__(256) void k2_gram(
    const unsigned short* __restrict__ Tb, const float* __restrict__ Nrm,
    float* __restrict__ Out) {
  __shared__ unsigned short sT[256 * 128];   // full T_b, 64KB, swizzled rows (256B)

  const int tid  = threadIdx.x;
  const int lane = tid & 63;
  const int w    = tid >> 6;        // 0..3
  const int b    = blockIdx.x >> 4;
  const int it   = blockIdx.x & 15;

  // stage full T_b: 4096 chunks of 16B, linear dest, inverse-swizzled source
#pragma unroll
  for (int i = 0; i < 16; ++i) {
    int c = tid + 256 * i;
    int row = c >> 4, ch = c & 15;
    gload_lds16(&Tb[(size_t)(b * L_ + row) * R_ + ((ch ^ (row & 7)) * 8)],
                &sT[c * 8]);
  }
  __syncthreads();

  f32x4 acc[4];
#pragma unroll
  for (int ct = 0; ct < 4; ++ct) { acc[ct][0]=0.f; acc[ct][1]=0.f; acc[ct][2]=0.f; acc[ct][3]=0.f; }

  const char* tb = reinterpret_cast<const char*>(&sT[0]);
#pragma unroll
  for (int s = 0; s < 4; ++s) {
    int koffb = s * 64 + ((lane >> 4) << 4);
    int ar = it * 16 + (lane & 15);
    short8 a = *reinterpret_cast<const short8*>(tb + ar * 256 + (koffb ^ ((ar & 7) << 4)));
#pragma unroll
    for (int ct = 0; ct < 4; ++ct) {
      int br = w * 64 + ct * 16 + (lane & 15);
      short8 bf = *reinterpret_cast<const short8*>(tb + br * 256 + (koffb ^ ((br & 7) << 4)));
      acc[ct] = __builtin_amdgcn_mfma_f32_16x16x32_bf16(a, bf, acc[ct], 0, 0, 0);
    }
  }

  const int col = lane & 15;
  float ni[4];
#pragma unroll
  for (int q = 0; q < 4; ++q)
    ni[q] = Nrm[b * L_ + it * 16 + ((lane >> 4) << 2) + q];
#pragma unroll
  for (int ct = 0; ct < 4; ++ct) {
    int j = w * 64 + ct * 16 + col;
    float nj = Nrm[b * L_ + j];
#pragma unroll
    for (int q = 0; q < 4; ++q) {
      int il = it * 16 + ((lane >> 4) << 2) + q;
      float v = ni[q] + nj - 2.0f * acc[ct][q];
      Out[(size_t)(b * L_ + il) * L_ + j] = fmaxf(v, 0.0f);
    }
  }
}

extern "C" void kernel_launch(void* const* d_in, const int* in_sizes, int n_in,
                              void* d_out, int out_size, void* d_ws, size_t ws_size,
                              hipStream_t stream) {
  const float* X = (const float*)d_in[0];   // [16,256,1024]
  const float* P = (const float*)d_in[1];   // [1024,128]
  float* Out = (float*)d_out;               // [16,256,256]
  char* ws = (char*)d_ws;
  unsigned short* PbT = (unsigned short*)ws;                               // 256 KB
  unsigned short* Tb  = (unsigned short*)(ws + (size_t)R_ * D_ * 2);       // 1 MB
  float* Nrm = (float*)(ws + (size_t)R_ * D_ * 2 + (size_t)M_ * R_ * 2);   // 16 KB

  k0_transpose_cast<<<64, 256, 0, stream>>>(P, PbT);
  k1_gemm<<<M_ / 16, 512, 0, stream>>>(X, PbT, Tb, Nrm);
  k2_gram<<<B_ * 16, 256, 0, stream>>>(Tb, Nrm, Out);
}

// Round 2
// 24.504 us; speedup vs baseline: 1.0981x; 1.0981x over previous
//
#include <hip/hip_runtime.h>
#include <stdint.h>

#define B_ 16
#define L_ 256
#define D_ 1024
#define R_ 128
#define M_ (B_*L_)   // 4096 rows of t

typedef short short8 __attribute__((ext_vector_type(8)));
typedef float f32x4 __attribute__((ext_vector_type(4)));

__device__ __forceinline__ unsigned short f2bf(float f) {
  union { float f; unsigned int u; } v; v.f = f;
  unsigned int r = v.u + 0x7FFFu + ((v.u >> 16) & 1u);  // RNE
  return (unsigned short)(r >> 16);
}
__device__ __forceinline__ float bf2f(unsigned short s) {
  union { unsigned int u; float f; } v; v.u = ((unsigned int)s) << 16;
  return v.f;
}
__device__ __forceinline__ void gload_lds16(const void* g, void* l) {
  __builtin_amdgcn_global_load_lds(
      (const __attribute__((address_space(1))) unsigned int*)g,
      (__attribute__((address_space(3))) unsigned int*)l, 16, 0, 0);
}

// ---------------- K0: P [1024][128] f32 -> PbT [128][1024] bf16 ----------------
// Lanes take consecutive n -> coalesced 256B reads; writes are scattered 16B (L2 absorbs).
__global__ __launch_bounds__(256) void k0_transpose_cast(
    const float* __restrict__ P, unsigned short* __restrict__ PbT) {
  int id = blockIdx.x * 256 + threadIdx.x;   // 0..16383
  int n  = id & 127;                         // consecutive across lanes
  int kc = id >> 7;                          // chunk of 8 k
  union { unsigned short s[8]; uint4 v; } u;
#pragma unroll
  for (int j = 0; j < 8; ++j) u.s[j] = f2bf(P[(kc * 8 + j) * R_ + n]);
  *reinterpret_cast<uint4*>(&PbT[(size_t)n * D_ + kc * 8]) = u.v;
}

// ---------------- K1: t = X @ P  (bf16 MFMA), + row norms ----------------
// BM=16, BN=128, BK=128. 512 threads = 8 waves, wave w owns cols [16w,16w+16).
// Double-buffered; stage issued before compute so the barrier drain == BW time.
__global__ __launch_bounds__(512) void k1_gemm(
    const float* __restrict__ X, const unsigned short* __restrict__ PbT,
    unsigned short* __restrict__ Tb, float* __restrict__ Nrm) {
  __shared__ unsigned short sX[2][16 * 128];    // 16 rows x 256B, swizzled
  __shared__ unsigned short sP[2][128 * 128];   // 128 rows x 256B, swizzled
  __shared__ float nacc[16][8];

  const int tid  = threadIdx.x;
  const int lane = tid & 63;
  const int w    = tid >> 6;          // wave 0..7
  const int m0   = blockIdx.x * 16;

  // X staging coords: thread covers (row, 4 consecutive k)
  const int xr = tid >> 5;            // 0..15
  const int xk = (tid & 31) * 4;      // 0..124

  f32x4 acc;
  acc[0] = 0.f; acc[1] = 0.f; acc[2] = 0.f; acc[3] = 0.f;

  auto stage = [&](int buf, int kt) {
    const int k0 = kt * 128;
    // X: load f32x4, cvt->bf16x4, swizzled ds_write_b64
    float4 xv = *reinterpret_cast<const float4*>(&X[(size_t)(m0 + xr) * D_ + k0 + xk]);
    uint2 p;
    p.x = (unsigned int)f2bf(xv.x) | ((unsigned int)f2bf(xv.y) << 16);
    p.y = (unsigned int)f2bf(xv.z) | ((unsigned int)f2bf(xv.w) << 16);
    int byte_in_row = (xk * 2) ^ ((xr & 7) << 4);
    *reinterpret_cast<uint2*>(reinterpret_cast<char*>(&sX[buf][0]) + xr * 256 + byte_in_row) = p;
    // P: global_load_lds 16B, linear LDS dest, inverse-swizzled global source
#pragma unroll
    for (int i = 0; i < 4; ++i) {
      int c = tid + 512 * i;          // chunk id 0..2047
      int row = c >> 4, ch = c & 15;  // 16 chunks per 256B row
      gload_lds16(&PbT[(size_t)row * D_ + k0 + ((ch ^ (row & 7)) * 8)],
                  reinterpret_cast<char*>(&sP[buf][0]) + c * 16);
    }
  };

  auto compute = [&](int buf) {
    const char* xb = reinterpret_cast<const char*>(&sX[buf][0]);
    const char* pb = reinterpret_cast<const char*>(&sP[buf][0]);
    const int nb = w * 16;
#pragma unroll
    for (int s = 0; s < 4; ++s) {
      int koffb = s * 64 + ((lane >> 4) << 4);   // byte offset of this lane's 8 k's
      int ar = lane & 15;
      short8 a = *reinterpret_cast<const short8*>(xb + ar * 256 + (koffb ^ ((ar & 7) << 4)));
      int br = nb + (lane & 15);
      short8 b = *reinterpret_cast<const short8*>(pb + br * 256 + (koffb ^ ((br & 7) << 4)));
      acc = __builtin_amdgcn_mfma_f32_16x16x32_bf16(a, b, acc, 0, 0, 0);
    }
  };

  stage(0, 0);
  __syncthreads();
  int buf = 0;
#pragma unroll
  for (int kt = 0; kt < 8; ++kt) {
    if (kt < 7) stage(buf ^ 1, kt + 1);
    compute(buf);
    __syncthreads();
    buf ^= 1;
  }

  // epilogue: write bf16 t, accumulate norms of the ROUNDED values
  const int nb = w * 16;
  const int col = lane & 15;
#pragma unroll
  for (int q = 0; q < 4; ++q) {
    int row = ((lane >> 4) << 2) + q;
    unsigned short hv = f2bf(acc[q]);
    Tb[(size_t)(m0 + row) * R_ + nb + col] = hv;
    float tr = bf2f(hv);
    float s = tr * tr;
    s += __shfl_xor(s, 1); s += __shfl_xor(s, 2);
    s += __shfl_xor(s, 4); s += __shfl_xor(s, 8);
    if (col == 0) nacc[row][w] = s;
  }
  __syncthreads();
  if (tid < 16) {
    float t = 0.f;
#pragma unroll
    for (int i = 0; i < 8; ++i) t += nacc[tid][i];
    Nrm[m0 + tid] = t;
  }
}

// ---------------- K2: per-batch Gram + distance epilogue ----------------
// block = (batch b, i-tile it, j-half jh). 512 blocks -> 2 blocks/CU (TLP hides stage drain).
// 256 threads = 4 waves, wave w owns j in [jh*128 + 32w, +32).
// LDS: half-tile layout [h][rows][128B] keeps global_load_lds dests linear.
__global__ __launch_bounds__(256) void k2_gram(
    const unsigned short* __restrict__ Tb, const float* __restrict__ Nrm,
    float* __restrict__ Out) {
  __shared__ unsigned short sI[2 * 16 * 64];    // [h][16][64 shorts] = 4KB
  __shared__ unsigned short sJ[2 * 128 * 64];   // [h][128][64 shorts] = 32KB

  const int tid  = threadIdx.x;
  const int lane = tid & 63;
  const int w    = tid >> 6;        // 0..3
  const int blk  = blockIdx.x;
  const int b    = blk >> 5;
  const int it   = (blk >> 1) & 15;
  const int jh   = blk & 1;

  // stage sI: 256 chunks of 16B (1/thread), linear dest = tid*16
  {
    int h = tid >> 7, row = (tid >> 3) & 15, ch = tid & 7;
    gload_lds16(&Tb[(size_t)(b * L_ + it * 16 + row) * R_ + h * 64 + ((ch ^ (row & 7)) * 8)],
                reinterpret_cast<char*>(sI) + tid * 16);
  }
  // stage sJ: 2048 chunks (8/thread), linear dest = c*16
#pragma unroll
  for (int i = 0; i < 8; ++i) {
    int c = tid + 256 * i;
    int h = c >> 10, row = (c >> 3) & 127, ch = c & 7;
    gload_lds16(&Tb[(size_t)(b * L_ + jh * 128 + row) * R_ + h * 64 + ((ch ^ (row & 7)) * 8)],
                reinterpret_cast<char*>(sJ) + c * 16);
  }
  __syncthreads();

  f32x4 acc[2];
#pragma unroll
  for (int ct = 0; ct < 2; ++ct) { acc[ct][0]=0.f; acc[ct][1]=0.f; acc[ct][2]=0.f; acc[ct][3]=0.f; }

  const char* ib = reinterpret_cast<const char*>(sI);
  const char* jb = reinterpret_cast<const char*>(sJ);
#pragma unroll
  for (int s = 0; s < 4; ++s) {
    int h = s >> 1;
    int col = (s & 1) * 64 + ((lane >> 4) << 4);
    int ar = lane & 15;
    short8 a = *reinterpret_cast<const short8*>(ib + h * 2048 + ar * 128 + (col ^ ((ar & 7) << 4)));
#pragma unroll
    for (int ct = 0; ct < 2; ++ct) {
      int br = w * 32 + ct * 16 + (lane & 15);
      short8 bv = *reinterpret_cast<const short8*>(jb + h * 16384 + br * 128 + (col ^ ((br & 7) << 4)));
      acc[ct] = __builtin_amdgcn_mfma_f32_16x16x32_bf16(a, bv, acc[ct], 0, 0, 0);
    }
  }

  const int col = lane & 15;
  float ni[4];
#pragma unroll
  for (int q = 0; q < 4; ++q)
    ni[q] = Nrm[b * L_ + it * 16 + ((lane >> 4) << 2) + q];
#pragma unroll
  for (int ct = 0; ct < 2; ++ct) {
    int j = jh * 128 + w * 32 + ct * 16 + col;
    float nj = Nrm[b * L_ + j];
#pragma unroll
    for (int q = 0; q < 4; ++q) {
      int il = it * 16 + ((lane >> 4) << 2) + q;
      float v = ni[q] + nj - 2.0f * acc[ct][q];
      Out[(size_t)(b * L_ + il) * L_ + j] = fmaxf(v, 0.0f);
    }
  }
}

extern "C" void kernel_launch(void* const* d_in, const int* in_sizes, int n_in,
                              void* d_out, int out_size, void* d_ws, size_t ws_size,
                              hipStream_t stream) {
  const float* X = (const float*)d_in[0];   // [16,256,1024]
  const float* P = (const float*)d_in[1];   // [1024,128]
  float* Out = (float*)d_out;               // [16,256,256]
  char* ws = (char*)d_ws;
  unsigned short* PbT = (unsigned short*)ws;                               // 256 KB
  unsigned short* Tb  = (unsigned short*)(ws + (size_t)R_ * D_ * 2);       // 1 MB
  float* Nrm = (float*)(ws + (size_t)R_ * D_ * 2 + (size_t)M_ * R_ * 2);   // 16 KB

  k0_transpose_cast<<<64, 256, 0, stream>>>(P, PbT);
  k1_gemm<<<M_ / 16, 512, 0, stream>>>(X, PbT, Tb, Nrm);
  k2_gram<<<B_ * 16 * 2, 256, 0, stream>>>(Tb, Nrm, Out);
}

// Round 3
// 22.528 us; speedup vs baseline: 1.1944x; 1.0877x over previous
//
#include <hip/hip_runtime.h>
#include <stdint.h>

#define B_ 16
#define L_ 256
#define D_ 1024
#define R_ 128
#define M_ (B_*L_)   // 4096 rows of t

typedef short short8 __attribute__((ext_vector_type(8)));
typedef float f32x4 __attribute__((ext_vector_type(4)));

__device__ __forceinline__ unsigned short f2bf(float f) {
  union { float f; unsigned int u; } v; v.f = f;
  unsigned int r = v.u + 0x7FFFu + ((v.u >> 16) & 1u);  // RNE
  return (unsigned short)(r >> 16);
}
__device__ __forceinline__ float bf2f(unsigned short s) {
  union { unsigned int u; float f; } v; v.u = ((unsigned int)s) << 16;
  return v.f;
}
__device__ __forceinline__ void gload_lds16(const void* g, void* l) {
  __builtin_amdgcn_global_load_lds(
      (const __attribute__((address_space(1))) unsigned int*)g,
      (__attribute__((address_space(3))) unsigned int*)l, 16, 0, 0);
}

// ---------------- K0: P [1024][128] f32 -> PbT [128][1024] bf16 ----------------
// Lanes take consecutive n -> coalesced 256B reads; writes are scattered 16B (L2 absorbs).
__global__ __launch_bounds__(256) void k0_transpose_cast(
    const float* __restrict__ P, unsigned short* __restrict__ PbT) {
  int id = blockIdx.x * 256 + threadIdx.x;   // 0..16383
  int n  = id & 127;                         // consecutive across lanes
  int kc = id >> 7;                          // chunk of 8 k
  union { unsigned short s[8]; uint4 v; } u;
#pragma unroll
  for (int j = 0; j < 8; ++j) u.s[j] = f2bf(P[(kc * 8 + j) * R_ + n]);
  *reinterpret_cast<uint4*>(&PbT[(size_t)n * D_ + kc * 8]) = u.v;
}

// ---------------- K1: t = X @ P  (bf16 MFMA) ----------------
// BM=16, BN=64, BK=128. grid=512 -> 2 blocks/CU (TLP hides the barrier vmcnt drain).
// 256 threads = 4 waves, wave w owns cols [nb0+16w, +16).
__global__ __launch_bounds__(256) void k1_gemm(
    const float* __restrict__ X, const unsigned short* __restrict__ PbT,
    unsigned short* __restrict__ Tb) {
  __shared__ unsigned short sX[2][16 * 128];    // 16 rows x 256B, swizzled  (8KB)
  __shared__ unsigned short sP[2][64 * 128];    // 64 rows x 256B, swizzled  (32KB)

  const int tid  = threadIdx.x;
  const int lane = tid & 63;
  const int w    = tid >> 6;          // wave 0..3
  // XCD-bijective swizzle (512 % 8 == 0): consecutive logical blocks -> same XCD
  const int lb   = (blockIdx.x & 7) * 64 + (blockIdx.x >> 3);
  const int m0   = (lb >> 1) * 16;
  const int nb0  = (lb & 1) * 64;

  f32x4 acc;
  acc[0] = 0.f; acc[1] = 0.f; acc[2] = 0.f; acc[3] = 0.f;

  auto stage = [&](int buf, int kt) {
    const int k0 = kt * 128;
    // X: 512 float4 chunks (2/thread), cvt->bf16x4, swizzled ds_write_b64
#pragma unroll
    for (int i = 0; i < 2; ++i) {
      int c = tid + 256 * i;
      int row = c >> 5;               // 0..15
      int kq  = (c & 31) * 4;         // float index 0..124
      float4 xv = *reinterpret_cast<const float4*>(&X[(size_t)(m0 + row) * D_ + k0 + kq]);
      uint2 p;
      p.x = (unsigned int)f2bf(xv.x) | ((unsigned int)f2bf(xv.y) << 16);
      p.y = (unsigned int)f2bf(xv.z) | ((unsigned int)f2bf(xv.w) << 16);
      int byte_in_row = (kq * 2) ^ ((row & 7) << 4);
      *reinterpret_cast<uint2*>(reinterpret_cast<char*>(&sX[buf][0]) + row * 256 + byte_in_row) = p;
    }
    // P: 1024 chunks of 16B (4/thread), linear LDS dest, inverse-swizzled global source
#pragma unroll
    for (int i = 0; i < 4; ++i) {
      int c = tid + 256 * i;
      int row = c >> 4, ch = c & 15;  // 16 chunks per 256B row
      gload_lds16(&PbT[(size_t)(nb0 + row) * D_ + k0 + ((ch ^ (row & 7)) * 8)],
                  reinterpret_cast<char*>(&sP[buf][0]) + c * 16);
    }
  };

  auto compute = [&](int buf) {
    const char* xb = reinterpret_cast<const char*>(&sX[buf][0]);
    const char* pb = reinterpret_cast<const char*>(&sP[buf][0]);
#pragma unroll
    for (int s = 0; s < 4; ++s) {
      int koffb = s * 64 + ((lane >> 4) << 4);
      int ar = lane & 15;
      short8 a = *reinterpret_cast<const short8*>(xb + ar * 256 + (koffb ^ ((ar & 7) << 4)));
      int br = w * 16 + (lane & 15);
      short8 b = *reinterpret_cast<const short8*>(pb + br * 256 + (koffb ^ ((br & 7) << 4)));
      acc = __builtin_amdgcn_mfma_f32_16x16x32_bf16(a, b, acc, 0, 0, 0);
    }
  };

  stage(0, 0);
  __syncthreads();
  int buf = 0;
#pragma unroll
  for (int kt = 0; kt < 8; ++kt) {
    if (kt < 7) stage(buf ^ 1, kt + 1);
    compute(buf);
    __syncthreads();
    buf ^= 1;
  }

  // epilogue: write bf16 t
  const int col = lane & 15;
#pragma unroll
  for (int q = 0; q < 4; ++q) {
    int row = ((lane >> 4) << 2) + q;
    Tb[(size_t)(m0 + row) * R_ + nb0 + w * 16 + col] = f2bf(acc[q]);
  }
}

// ---------------- K2: per-batch Gram + distance epilogue ----------------
// block = (b, i-tile it, j-quarter jq). grid=1024 -> 4 blocks/CU.
// 256 threads = 4 waves, wave w owns j in [jq*64 + 16w, +16).
// Norms computed in-block from the staged (rounded) bf16 rows -> no Nrm workspace.
__global__ __launch_bounds__(256) void k2_gram(
    const unsigned short* __restrict__ Tb, float* __restrict__ Out) {
  __shared__ unsigned short sI[16 * 128];    // 4KB, swizzled 256B rows
  __shared__ unsigned short sJ[64 * 128];    // 16KB
  __shared__ float nI[16], nJ[64];

  const int tid  = threadIdx.x;
  const int lane = tid & 63;
  const int w    = tid >> 6;        // 0..3
  const int blk  = blockIdx.x;
  const int b    = blk >> 6;
  const int it   = (blk >> 2) & 15;
  const int jq   = blk & 3;

  // stage sI: 256 chunks of 16B (1/thread)
  {
    int row = tid >> 4, ch = tid & 15;
    gload_lds16(&Tb[(size_t)(b * L_ + it * 16 + row) * R_ + ((ch ^ (row & 7)) * 8)],
                reinterpret_cast<char*>(sI) + tid * 16);
  }
  // stage sJ: 1024 chunks (4/thread)
#pragma unroll
  for (int i = 0; i < 4; ++i) {
    int c = tid + 256 * i;
    int row = c >> 4, ch = c & 15;
    gload_lds16(&Tb[(size_t)(b * L_ + jq * 64 + row) * R_ + ((ch ^ (row & 7)) * 8)],
                reinterpret_cast<char*>(sJ) + c * 16);
  }
  __syncthreads();

  // norms: threads 0..159, row = t>>1 (0..15 -> sI, 16..79 -> sJ), half = t&1
  if (tid < 160) {
    int row = tid >> 1, h = tid & 1;
    const char* base = (row < 16) ? reinterpret_cast<const char*>(sI)
                                  : reinterpret_cast<const char*>(sJ);
    int r = (row < 16) ? row : row - 16;
    float s = 0.f;
#pragma unroll
    for (int j = 0; j < 8; ++j) {
      short8 v = *reinterpret_cast<const short8*>(base + r * 256 + ((h * 128 + j * 16) ^ ((r & 7) << 4)));
#pragma unroll
      for (int e = 0; e < 8; ++e) { float f = bf2f((unsigned short)v[e]); s += f * f; }
    }
    s += __shfl_xor(s, 1);
    if (h == 0) { if (row < 16) nI[row] = s; else nJ[row - 16] = s; }
  }

  // Gram via MFMA
  f32x4 acc;
  acc[0] = 0.f; acc[1] = 0.f; acc[2] = 0.f; acc[3] = 0.f;
  const char* ib = reinterpret_cast<const char*>(sI);
  const char* jb = reinterpret_cast<const char*>(sJ);
#pragma unroll
  for (int s = 0; s < 4; ++s) {
    int koffb = s * 64 + ((lane >> 4) << 4);
    int ar = lane & 15;
    short8 a = *reinterpret_cast<const short8*>(ib + ar * 256 + (koffb ^ ((ar & 7) << 4)));
    int br = w * 16 + (lane & 15);
    short8 bv = *reinterpret_cast<const short8*>(jb + br * 256 + (koffb ^ ((br & 7) << 4)));
    acc = __builtin_amdgcn_mfma_f32_16x16x32_bf16(a, bv, acc, 0, 0, 0);
  }
  __syncthreads();   // nI/nJ visible to all

  const int col = lane & 15;
  const int jj = w * 16 + col;
  const float nj = nJ[jj];
#pragma unroll
  for (int q = 0; q < 4; ++q) {
    int ir = ((lane >> 4) << 2) + q;
    float v = nI[ir] + nj - 2.0f * acc[q];
    Out[(size_t)(b * L_ + it * 16 + ir) * L_ + jq * 64 + jj] = fmaxf(v, 0.0f);
  }
}

extern "C" void kernel_launch(void* const* d_in, const int* in_sizes, int n_in,
                              void* d_out, int out_size, void* d_ws, size_t ws_size,
                              hipStream_t stream) {
  const float* X = (const float*)d_in[0];   // [16,256,1024]
  const float* P = (const float*)d_in[1];   // [1024,128]
  float* Out = (float*)d_out;               // [16,256,256]
  char* ws = (char*)d_ws;
  unsigned short* PbT = (unsigned short*)ws;                               // 256 KB
  unsigned short* Tb  = (unsigned short*)(ws + (size_t)R_ * D_ * 2);       // 1 MB

  k0_transpose_cast<<<64, 256, 0, stream>>>(P, PbT);
  k1_gemm<<<M_ / 16 * 2, 256, 0, stream>>>(X, PbT, Tb);
  k2_gram<<<B_ * 16 * 4, 256, 0, stream>>>(Tb, Out);
}